// Round 6
// baseline (1269.333 us; speedup 1.0000x reference)
//
#include <hip/hip_runtime.h>

// y[m][n] = sum_k x[m][k] * (w[n][k]*scale[n]) + bias[n]
// M=8192, N=11008, K=4096. fp32 in/out, bf16 MFMA compute.
//
// Structure: R2's proven ring-4 (256x256 tile, BK=32, 8 waves 2Mx4N, 128 KB
// LDS, global_load_lds + counted vmcnt(8), 1 barrier/step, XOR swizzle with
// 0 conflicts, XCD block swizzle) with ONE change: per-wave software
// pipelining of the step body — chunks of {1 ds_read (next A frag) -> 4 MFMA}
// pinned by sched_group_barrier, so each wave's LDS reads fly under its own
// MFMAs instead of the chip-wide read-burst/MFMA-burst lockstep alternation.
#define M_DIM 8192
#define N_DIM 11008
#define K_DIM 4096
#define BM 256
#define BN 256
#define BK 32
#define NT (K_DIM / BK)   // 128 K-steps
#define TM (M_DIM / BM)   // 32
#define TN (N_DIM / BN)   // 43
#define NWG (TM * TN)     // 1376 (divisible by 8)

typedef __attribute__((ext_vector_type(8))) short bf16x8;
typedef __attribute__((ext_vector_type(8))) unsigned short u16x8;
typedef __attribute__((ext_vector_type(4))) float f32x4;

__device__ __forceinline__ unsigned short f2bf(float f) {
  union { float f; unsigned u; } v; v.f = f;
  unsigned r = v.u + 0x7FFFu + ((v.u >> 16) & 1u);  // RNE
  return (unsigned short)(r >> 16);
}

__device__ __forceinline__ void gload_lds16(const unsigned short* g, unsigned short* l) {
  __builtin_amdgcn_global_load_lds(
      (const __attribute__((address_space(1))) void*)g,
      (__attribute__((address_space(3))) void*)l, 16, 0, 0);
}

// involution swizzle on byte offset within a 16 KB panel (256 rows x 64 B):
// XOR byte bits 4-5 with row bits 1-2 -> conflict-free ds_read_b128 (R2: 0).
__device__ __forceinline__ int swz(int b) { return b ^ ((b >> 3) & 0x30); }

// ---- pre-convert kernels (memory-bound) ----
__global__ void cvt_x_kernel(const float* __restrict__ in, unsigned short* __restrict__ o) {
  size_t i = (size_t)blockIdx.x * 256 + threadIdx.x;
  const float4* p = (const float4*)in + i * 2;
  float4 f0 = p[0], f1 = p[1];
  u16x8 v;
  v[0] = f2bf(f0.x); v[1] = f2bf(f0.y); v[2] = f2bf(f0.z); v[3] = f2bf(f0.w);
  v[4] = f2bf(f1.x); v[5] = f2bf(f1.y); v[6] = f2bf(f1.z); v[7] = f2bf(f1.w);
  *((u16x8*)o + i) = v;
}

__global__ void cvt_w_kernel(const float* __restrict__ in, const float* __restrict__ sc,
                             unsigned short* __restrict__ o) {
  size_t i = (size_t)blockIdx.x * 256 + threadIdx.x;
  float s = sc[i >> 9];  // 4096/8 = 512 packs per row
  const float4* p = (const float4*)in + i * 2;
  float4 f0 = p[0], f1 = p[1];
  u16x8 v;
  v[0] = f2bf(f0.x * s); v[1] = f2bf(f0.y * s); v[2] = f2bf(f0.z * s); v[3] = f2bf(f0.w * s);
  v[4] = f2bf(f1.x * s); v[5] = f2bf(f1.y * s); v[6] = f2bf(f1.z * s); v[7] = f2bf(f1.w * s);
  *((u16x8*)o + i) = v;
}

// ---- GEMM ----
__launch_bounds__(512, 2)
__global__ void gemm_kernel(const unsigned short* __restrict__ xb,
                            const unsigned short* __restrict__ wb,
                            const float* __restrict__ bias,
                            float* __restrict__ out) {
  // 4-ring of K-step panels: each panel = 256 rows x 32 k bf16 = 16 KB.
  __shared__ unsigned short As[4 * 8192];  // 64 KB
  __shared__ unsigned short Bs[4 * 8192];  // 64 KB

  const int tid = threadIdx.x;
  const int lane = tid & 63;
  const int wave = tid >> 6;
  const int wr = wave >> 2;   // 0..1 -> 128-row half of A
  const int wc = wave & 3;    // 0..3 -> 64-col slice of B

  // T1: XCD-aware swizzle (bijective, NWG%8==0), column-major within chunk.
  int orig = blockIdx.x;
  int wg = (orig & 7) * (NWG / 8) + (orig >> 3);
  int bx = wg / TM;           // N tile 0..42
  int by = wg % TM;           // M tile 0..31
  const int rowBase = by * BM;
  const int colBase = bx * BN;

  f32x4 acc[8][4] = {};

  const int fr = lane & 15;
  const int q16 = (lane >> 4) * 16;  // byte col within 64 B row

  float bias_v[4];
#pragma unroll
  for (int n = 0; n < 4; ++n)
    bias_v[n] = bias[colBase + wc * 64 + n * 16 + fr];

  // staging: per thread 2 chunks of A + 2 of B per K-step; linear LDS dest
  // (wave-uniform base + lane*16), pre-swizzled global source (rule #21).
  int p0 = tid * 16;
  int L0 = swz(p0), L1 = swz(p0 + 8192);
  const int sr0 = L0 >> 6, sc0 = (L0 & 63) >> 1;
  const int sr1 = (L1 >> 6), sc1 = (L1 & 63) >> 1;  // L1>>6 in [128,256)

  auto stageA = [&](int kt) {
    int b = kt & 3;
    const unsigned short* src = xb + (size_t)kt * BK;
    gload_lds16(src + (size_t)(rowBase + sr0) * K_DIM + sc0, &As[b * 8192 + (p0 >> 1)]);
    gload_lds16(src + (size_t)(rowBase + sr1) * K_DIM + sc1, &As[b * 8192 + ((p0 + 8192) >> 1)]);
  };
  auto stageB = [&](int kt) {
    int b = kt & 3;
    const unsigned short* src = wb + (size_t)kt * BK;
    gload_lds16(src + (size_t)(colBase + sr0) * K_DIM + sc0, &Bs[b * 8192 + (p0 >> 1)]);
    gload_lds16(src + (size_t)(colBase + sr1) * K_DIM + sc1, &Bs[b * 8192 + ((p0 + 8192) >> 1)]);
  };

  // One K-step, software-pipelined per wave:
  //   prologue: read all 4 B frags + A frag 0; issue stage (VMEM, floats)
  //   8 chunks: {ds_read A frag mi+1} -> {4 MFMA row mi}, a[] register-rotated
  //   sched_group_barrier pins the [DS1, MFMA4] interleave (anti-bunching).
  auto step = [&](int t, bool doStage) {
    const char* Ab = (const char*)&As[(t & 3) * 8192];
    const char* Bb = (const char*)&Bs[(t & 3) * 8192];
    bf16x8 b[4], a[2];
#pragma unroll
    for (int nj = 0; nj < 4; ++nj) {
      int L = (wc * 64 + nj * 16 + fr) * 64 + q16;
      b[nj] = *(const bf16x8*)(Bb + swz(L));
    }
    {
      int L = (wr * 128 + fr) * 64 + q16;
      a[0] = *(const bf16x8*)(Ab + swz(L));
    }
    if (doStage) { stageA(t + 3); stageB(t + 3); }
    __builtin_amdgcn_s_setprio(1);
#pragma unroll
    for (int mi = 0; mi < 8; ++mi) {
      if (mi < 7) {
        int L = (wr * 128 + (mi + 1) * 16 + fr) * 64 + q16;
        a[(mi + 1) & 1] = *(const bf16x8*)(Ab + swz(L));
        __builtin_amdgcn_sched_group_barrier(0x100, 1, 0);  // 1 DS_READ here
      }
#pragma unroll
      for (int nj = 0; nj < 4; ++nj)
        acc[mi][nj] = __builtin_amdgcn_mfma_f32_16x16x32_bf16(a[mi & 1], b[nj], acc[mi][nj], 0, 0, 0);
      __builtin_amdgcn_sched_group_barrier(0x8, 4, 0);      // 4 MFMA here
    }
    __builtin_amdgcn_s_setprio(0);
  };

  // prologue: stage pairs 0,1,2 (12 loads/thread), wait pair 0 (8 in flight)
  stageA(0); stageB(0);
  stageA(1); stageB(1);
  stageA(2); stageB(2);
  asm volatile("s_waitcnt vmcnt(8)" ::: "memory");
  __builtin_amdgcn_s_barrier();

  // main loop: compute tile t, stage t+3; vmcnt(8) -> pair t+1 landed, pairs
  // t+2,t+3 in flight (never drained to 0). Slot (t+3)&3 was last read at
  // step t-1, whose ds_reads completed before its consuming MFMAs (which
  // precede the closing barrier) -> race-free. Ledger identical to R2.
  for (int t = 0; t < NT - 3; ++t) {
    step(t, true);
    asm volatile("s_waitcnt vmcnt(8)" ::: "memory");
    __builtin_amdgcn_s_barrier();
  }
  // tail: drain 4 -> 0
  step(NT - 3, false);
  asm volatile("s_waitcnt vmcnt(4)" ::: "memory");
  __builtin_amdgcn_s_barrier();
  step(NT - 2, false);
  asm volatile("s_waitcnt vmcnt(0)" ::: "memory");
  __builtin_amdgcn_s_barrier();
  step(NT - 1, false);

  // epilogue: C/D layout col=lane&15, row=(lane>>4)*4+reg (m89/m91)
  const int r0 = (lane >> 4) * 4;
#pragma unroll
  for (int m = 0; m < 8; ++m) {
#pragma unroll
    for (int r = 0; r < 4; ++r) {
      size_t row = (size_t)(rowBase + wr * 128 + m * 16 + r0 + r);
      float* po = out + row * N_DIM + colBase + wc * 64 + fr;
#pragma unroll
      for (int n = 0; n < 4; ++n)
        po[n * 16] = acc[m][n][r] + bias_v[n];
    }
  }
}

extern "C" void kernel_launch(void* const* d_in, const int* in_sizes, int n_in,
                              void* d_out, int out_size, void* d_ws, size_t ws_size,
                              hipStream_t stream) {
  const float* x = (const float*)d_in[0];   // [8192][4096]
  const float* w = (const float*)d_in[1];   // [11008][4096]
  const float* sc = (const float*)d_in[2];  // [11008]
  const float* bi = (const float*)d_in[3];  // [11008]
  float* out = (float*)d_out;

  const size_t xe = (size_t)M_DIM * K_DIM;
  const size_t we = (size_t)N_DIM * K_DIM;
  unsigned short* xb = (unsigned short*)d_ws;
  unsigned short* wb = xb + xe;

  cvt_x_kernel<<<(unsigned)(xe / 8 / 256), 256, 0, stream>>>(x, xb);
  cvt_w_kernel<<<(unsigned)(we / 8 / 256), 256, 0, stream>>>(w, sc, wb);
  gemm_kernel<<<NWG, 512, 0, stream>>>(xb, wb, bi, out);
}

// Round 7
// 1108.606 us; speedup vs baseline: 1.1450x; 1.1450x over previous
//
#include <hip/hip_runtime.h>

// y[m][n] = sum_k x[m][k] * (w[n][k]*scale[n]) + bias[n]
// M=8192, N=11008, K=4096. fp32 in/out, bf16 MFMA compute.
//
// Structure: 128x128 tile, BK=32, 4 waves (2x2), ring-4 LDS panels (64 KB
// -> 2 blocks/CU for cross-block TLP), global_load_lds + counted vmcnt(8)
// (T4, R2-proven ledger), read-side XOR swizzle (T2, 0 conflicts), setprio
// (T5, cross-block diversity), XCD block swizzle (T1). No sched_group_barrier
// (R6: pinning regressed), compiler schedules the step body.
#define M_DIM 8192
#define N_DIM 11008
#define K_DIM 4096
#define BM 128
#define BN 128
#define BK 32
#define NT (K_DIM / BK)   // 128 K-steps
#define TM (M_DIM / BM)   // 64
#define TN (N_DIM / BN)   // 86
#define NWG (TM * TN)     // 5504 (divisible by 8)

typedef __attribute__((ext_vector_type(8))) short bf16x8;
typedef __attribute__((ext_vector_type(8))) unsigned short u16x8;
typedef __attribute__((ext_vector_type(4))) float f32x4;

__device__ __forceinline__ unsigned short f2bf(float f) {
  union { float f; unsigned u; } v; v.f = f;
  unsigned r = v.u + 0x7FFFu + ((v.u >> 16) & 1u);  // RNE
  return (unsigned short)(r >> 16);
}

__device__ __forceinline__ void gload_lds16(const unsigned short* g, unsigned short* l) {
  __builtin_amdgcn_global_load_lds(
      (const __attribute__((address_space(1))) void*)g,
      (__attribute__((address_space(3))) void*)l, 16, 0, 0);
}

// involution swizzle on byte offset within an 8 KB panel (128 rows x 64 B):
// XOR byte bits 4-5 with row bits 1-2 -> conflict-free ds_read_b128
// (R2-verified: 0 conflicts at identical row-stride/lane-group geometry).
__device__ __forceinline__ int swz(int b) { return b ^ ((b >> 3) & 0x30); }

// ---- pre-convert kernels (memory-bound) ----
__global__ void cvt_x_kernel(const float* __restrict__ in, unsigned short* __restrict__ o) {
  size_t i = (size_t)blockIdx.x * 256 + threadIdx.x;
  const float4* p = (const float4*)in + i * 2;
  float4 f0 = p[0], f1 = p[1];
  u16x8 v;
  v[0] = f2bf(f0.x); v[1] = f2bf(f0.y); v[2] = f2bf(f0.z); v[3] = f2bf(f0.w);
  v[4] = f2bf(f1.x); v[5] = f2bf(f1.y); v[6] = f2bf(f1.z); v[7] = f2bf(f1.w);
  *((u16x8*)o + i) = v;
}

__global__ void cvt_w_kernel(const float* __restrict__ in, const float* __restrict__ sc,
                             unsigned short* __restrict__ o) {
  size_t i = (size_t)blockIdx.x * 256 + threadIdx.x;
  float s = sc[i >> 9];  // 4096/8 = 512 packs per row
  const float4* p = (const float4*)in + i * 2;
  float4 f0 = p[0], f1 = p[1];
  u16x8 v;
  v[0] = f2bf(f0.x * s); v[1] = f2bf(f0.y * s); v[2] = f2bf(f0.z * s); v[3] = f2bf(f0.w * s);
  v[4] = f2bf(f1.x * s); v[5] = f2bf(f1.y * s); v[6] = f2bf(f1.z * s); v[7] = f2bf(f1.w * s);
  *((u16x8*)o + i) = v;
}

// ---- GEMM ----
__launch_bounds__(256, 2)
__global__ void gemm_kernel(const unsigned short* __restrict__ xb,
                            const unsigned short* __restrict__ wb,
                            const float* __restrict__ bias,
                            float* __restrict__ out) {
  // 4-ring of K-step panels: each panel = 128 rows x 32 k bf16 = 8 KB.
  __shared__ unsigned short As[4 * 4096];  // 32 KB
  __shared__ unsigned short Bs[4 * 4096];  // 32 KB  (64 KB total -> 2 blocks/CU)

  const int tid = threadIdx.x;
  const int lane = tid & 63;
  const int wave = tid >> 6;
  const int wr = wave >> 1;   // 0..1 -> 64-row half of A
  const int wc = wave & 1;    // 0..1 -> 64-col half of B

  // T1: XCD-aware swizzle (bijective, NWG%8==0), column-major within chunk
  // (consecutive blocks in a chunk share the B panel).
  int orig = blockIdx.x;
  int wg = (orig & 7) * (NWG / 8) + (orig >> 3);
  int bx = wg / TM;           // N tile 0..85
  int by = wg % TM;           // M tile 0..63
  const int rowBase = by * BM;
  const int colBase = bx * BN;

  f32x4 acc[4][4] = {};

  const int fr = lane & 15;
  const int q16 = (lane >> 4) * 16;  // byte col within 64 B row

  float bias_v[4];
#pragma unroll
  for (int n = 0; n < 4; ++n)
    bias_v[n] = bias[colBase + wc * 64 + n * 16 + fr];

  // staging: per thread 2 chunks of A + 2 of B per K-step (panel = 8 KB =
  // 2 x 256 threads x 16 B). Linear LDS dest, pre-swizzled global source.
  int p0 = tid * 16;                       // [0, 4096)
  int L0 = swz(p0), L1 = swz(p0 + 4096);
  const int sr0 = L0 >> 6, sc0 = (L0 & 63) >> 1;
  const int sr1 = L1 >> 6, sc1 = (L1 & 63) >> 1;  // rows 64..127

  auto stageA = [&](int kt) {
    int b = kt & 3;
    const unsigned short* src = xb + (size_t)kt * BK;
    gload_lds16(src + (size_t)(rowBase + sr0) * K_DIM + sc0, &As[b * 4096 + (p0 >> 1)]);
    gload_lds16(src + (size_t)(rowBase + sr1) * K_DIM + sc1, &As[b * 4096 + ((p0 + 4096) >> 1)]);
  };
  auto stageB = [&](int kt) {
    int b = kt & 3;
    const unsigned short* src = wb + (size_t)kt * BK;
    gload_lds16(src + (size_t)(colBase + sr0) * K_DIM + sc0, &Bs[b * 4096 + (p0 >> 1)]);
    gload_lds16(src + (size_t)(colBase + sr1) * K_DIM + sc1, &Bs[b * 4096 + ((p0 + 4096) >> 1)]);
  };

  auto step = [&](int t, bool doStage) {
    const char* Ab = (const char*)&As[(t & 3) * 4096];
    const char* Bb = (const char*)&Bs[(t & 3) * 4096];
    bf16x8 a[4], b[4];
#pragma unroll
    for (int n = 0; n < 4; ++n) {
      int L = (wc * 64 + n * 16 + fr) * 64 + q16;
      b[n] = *(const bf16x8*)(Bb + swz(L));
    }
#pragma unroll
    for (int m = 0; m < 4; ++m) {
      int L = (wr * 64 + m * 16 + fr) * 64 + q16;
      a[m] = *(const bf16x8*)(Ab + swz(L));
    }
    if (doStage) { stageA(t + 3); stageB(t + 3); }
    __builtin_amdgcn_s_setprio(1);
#pragma unroll
    for (int m = 0; m < 4; ++m)
#pragma unroll
      for (int n = 0; n < 4; ++n)
        acc[m][n] = __builtin_amdgcn_mfma_f32_16x16x32_bf16(a[m], b[n], acc[m][n], 0, 0, 0);
    __builtin_amdgcn_s_setprio(0);
  };

  // prologue: stage pairs 0,1,2 (12 loads/thread), wait pair 0 (8 in flight)
  stageA(0); stageB(0);
  stageA(1); stageB(1);
  stageA(2); stageB(2);
  asm volatile("s_waitcnt vmcnt(8)" ::: "memory");
  __builtin_amdgcn_s_barrier();

  // main loop: compute tile t, stage t+3; vmcnt(8) -> pair t+1 landed, pairs
  // t+2,t+3 in flight (never drained to 0). Slot (t+3)&3 was last read at
  // step t-1, whose ds_reads completed before its consuming MFMAs (which
  // precede the closing barrier) -> race-free. Ledger identical to R2.
  for (int t = 0; t < NT - 3; ++t) {
    step(t, true);
    asm volatile("s_waitcnt vmcnt(8)" ::: "memory");
    __builtin_amdgcn_s_barrier();
  }
  // tail: drain 4 -> 0
  step(NT - 3, false);
  asm volatile("s_waitcnt vmcnt(4)" ::: "memory");
  __builtin_amdgcn_s_barrier();
  step(NT - 2, false);
  asm volatile("s_waitcnt vmcnt(0)" ::: "memory");
  __builtin_amdgcn_s_barrier();
  step(NT - 1, false);

  // epilogue: C/D layout col=lane&15, row=(lane>>4)*4+reg (m89/m91)
  const int r0 = (lane >> 4) * 4;
#pragma unroll
  for (int m = 0; m < 4; ++m) {
#pragma unroll
    for (int r = 0; r < 4; ++r) {
      size_t row = (size_t)(rowBase + wr * 64 + m * 16 + r0 + r);
      float* po = out + row * N_DIM + colBase + wc * 64 + fr;
#pragma unroll
      for (int n = 0; n < 4; ++n)
        po[n * 16] = acc[m][n][r] + bias_v[n];
    }
  }
}

extern "C" void kernel_launch(void* const* d_in, const int* in_sizes, int n_in,
                              void* d_out, int out_size, void* d_ws, size_t ws_size,
                              hipStream_t stream) {
  const float* x = (const float*)d_in[0];   // [8192][4096]
  const float* w = (const float*)d_in[1];   // [11008][4096]
  const float* sc = (const float*)d_in[2];  // [11008]
  const float* bi = (const float*)d_in[3];  // [11008]
  float* out = (float*)d_out;

  const size_t xe = (size_t)M_DIM * K_DIM;
  const size_t we = (size_t)N_DIM * K_DIM;
  unsigned short* xb = (unsigned short*)d_ws;
  unsigned short* wb = xb + xe;

  cvt_x_kernel<<<(unsigned)(xe / 8 / 256), 256, 0, stream>>>(x, xb);
  cvt_w_kernel<<<(unsigned)(we / 8 / 256), 256, 0, stream>>>(w, sc, wb);
  gemm_kernel<<<NWG, 256, 0, stream>>>(xb, wb, bi, out);
}

// Round 10
// 925.692 us; speedup vs baseline: 1.3712x; 1.1976x over previous
//
#include <hip/hip_runtime.h>

// y[m][n] = sum_k x[m][k] * (w[n][k]*scale[n]) + bias[n]
// M=8192, N=11008, K=4096. fp32 in/out, bf16 MFMA compute.
//
// m201-style 8-phase schedule: 256x256 tile, 8 waves (2Mx4N), BK=64,
// double-buffered LDS (2dbuf x 2half x 128x64 x {A,B} x 2B = 128 KB).
// Per phase: {ds_reads (4-12 b128) + stage ONE half-tile (2 gload_lds)
// -> barrier -> 16-MFMA quadrant (setprio) -> barrier}; counted vmcnt(4)
// at phases 4 and 8 only (never 0 mid-loop). Race-free stagger derived
// from region last-reads (B: ph2, A: ph3 within each K-tile's 4 phases).
// Read-side XOR swizzle (T2), XCD block swizzle (T1).
#define M_DIM 8192
#define N_DIM 11008
#define K_DIM 4096
#define BM 256
#define BN 256
#define BK 64
#define NT (K_DIM / BK)   // 64 K-tiles
#define NIT (NT / 2)      // 32 iterations, 2 K-tiles each
#define TM (M_DIM / BM)   // 32
#define TN (N_DIM / BN)   // 43
#define NWG (TM * TN)     // 1376 (divisible by 8)

typedef __attribute__((ext_vector_type(8))) short bf16x8;
typedef __attribute__((ext_vector_type(8))) unsigned short u16x8;
typedef __attribute__((ext_vector_type(4))) float f32x4;

__device__ __forceinline__ unsigned short f2bf(float f) {
  union { float f; unsigned u; } v; v.f = f;
  unsigned r = v.u + 0x7FFFu + ((v.u >> 16) & 1u);  // RNE
  return (unsigned short)(r >> 16);
}

__device__ __forceinline__ void gload_lds16(const unsigned short* g, unsigned short* l) {
  __builtin_amdgcn_global_load_lds(
      (const __attribute__((address_space(1))) void*)g,
      (__attribute__((address_space(3))) void*)l, 16, 0, 0);
}

// Involution swizzle within a 16 KB half-tile (128 rows x 128 B): XOR the
// 16B-unit index (bits 4-6) with row bits 0-2 (bits 7-9). A 16-lane frag
// read (16 consecutive rows, fixed 16B col) spreads across all 8 units =
// 32 banks -> 2 lanes/bank = free (m136; R2 measured 0 conflicts on the
// 64B-row analog of this swizzle).
__device__ __forceinline__ int swz(int b) { return b ^ (((b >> 7) & 7) << 4); }

#define BAR() asm volatile("s_barrier" ::: "memory")

// ---- pre-convert kernels (memory-bound) ----
__global__ void cvt_x_kernel(const float* __restrict__ in, unsigned short* __restrict__ o) {
  size_t i = (size_t)blockIdx.x * 256 + threadIdx.x;
  const float4* p = (const float4*)in + i * 2;
  float4 f0 = p[0], f1 = p[1];
  u16x8 v;
  v[0] = f2bf(f0.x); v[1] = f2bf(f0.y); v[2] = f2bf(f0.z); v[3] = f2bf(f0.w);
  v[4] = f2bf(f1.x); v[5] = f2bf(f1.y); v[6] = f2bf(f1.z); v[7] = f2bf(f1.w);
  *((u16x8*)o + i) = v;
}

__global__ void cvt_w_kernel(const float* __restrict__ in, const float* __restrict__ sc,
                             unsigned short* __restrict__ o) {
  size_t i = (size_t)blockIdx.x * 256 + threadIdx.x;
  float s = sc[i >> 9];  // 4096/8 = 512 packs per row
  const float4* p = (const float4*)in + i * 2;
  float4 f0 = p[0], f1 = p[1];
  u16x8 v;
  v[0] = f2bf(f0.x * s); v[1] = f2bf(f0.y * s); v[2] = f2bf(f0.z * s); v[3] = f2bf(f0.w * s);
  v[4] = f2bf(f1.x * s); v[5] = f2bf(f1.y * s); v[6] = f2bf(f1.z * s); v[7] = f2bf(f1.w * s);
  *((u16x8*)o + i) = v;
}

// ---- GEMM ----
__launch_bounds__(512, 2)
__global__ void gemm_kernel(const unsigned short* __restrict__ xb,
                            const unsigned short* __restrict__ wb,
                            const float* __restrict__ bias,
                            float* __restrict__ out) {
  // [dbuf][half]: half-tile = 128 rows x 64 k bf16 = 16 KB. Total 128 KB.
  __shared__ unsigned short As[2][2][8192];
  __shared__ unsigned short Bs[2][2][8192];

  const int tid = threadIdx.x;
  const int lane = tid & 63;
  const int wave = tid >> 6;
  const int wr = wave >> 2;   // 0..1 -> 128-row half of A (= A half index)
  const int wc = wave & 3;    // 0..3 -> 64-col slice of B (half = wc>>1)

  // T1: XCD-aware swizzle (bijective, NWG%8==0), column-major within chunk.
  int orig = blockIdx.x;
  int wg = (orig & 7) * (NWG / 8) + (orig >> 3);
  int bx = wg / TM;           // N tile 0..42
  int by = wg % TM;           // M tile 0..31
  const int rowBase = by * BM;
  const int colBase = bx * BN;

  f32x4 acc[8][4] = {};

  const int fr = lane & 15;
  const int q16 = (lane >> 4) * 16;  // byte col of the 8-k sub-frag

  float bias_v[4];
#pragma unroll
  for (int n = 0; n < 4; ++n)
    bias_v[n] = bias[colBase + wc * 64 + n * 16 + fr];

  // staging: half-tile = 16 KB = 512 threads x 2 x 16 B. Linear LDS dest,
  // pre-swizzled global source (rule #21: same involution both sides).
  const int L0 = tid * 16, L1 = L0 + 8192;
  const int S0 = swz(L0), S1 = swz(L1);
  const int sr0 = S0 >> 7, sc0_ = (S0 & 127) >> 1;
  const int sr1 = S1 >> 7, sc1_ = (S1 & 127) >> 1;

  auto stageA = [&](int kt, int half) {
    const unsigned short* src =
        xb + (size_t)(rowBase + half * 128) * K_DIM + (size_t)kt * BK;
    unsigned short* dst = &As[kt & 1][half][0];
    gload_lds16(src + (size_t)sr0 * K_DIM + sc0_, dst + (L0 >> 1));
    gload_lds16(src + (size_t)sr1 * K_DIM + sc1_, dst + (L1 >> 1));
  };
  auto stageB = [&](int kt, int half) {
    const unsigned short* src =
        wb + (size_t)(colBase + half * 128) * K_DIM + (size_t)kt * BK;
    unsigned short* dst = &Bs[kt & 1][half][0];
    gload_lds16(src + (size_t)sr0 * K_DIM + sc0_, dst + (L0 >> 1));
    gload_lds16(src + (size_t)sr1 * K_DIM + sc1_, dst + (L1 >> 1));
  };

  bf16x8 aF[8], bLo[4], bHi[4];

  auto rdA = [&](int d, int qm) {
    const char* Ab = (const char*)&As[d][wr][0];
#pragma unroll
    for (int mi = 0; mi < 4; ++mi)
#pragma unroll
      for (int ks = 0; ks < 2; ++ks) {
        int b = (qm * 64 + mi * 16 + fr) * 128 + ks * 64 + q16;
        aF[mi * 2 + ks] = *(const bf16x8*)(Ab + swz(b));
      }
  };
  auto rdB = [&](int d, int qn, bf16x8* bf) {
    const char* Bb = (const char*)&Bs[d][wc >> 1][0];
#pragma unroll
    for (int nj = 0; nj < 2; ++nj)
#pragma unroll
      for (int ks = 0; ks < 2; ++ks) {
        int b = ((wc & 1) * 64 + qn * 32 + nj * 16 + fr) * 128 + ks * 64 + q16;
        bf[nj * 2 + ks] = *(const bf16x8*)(Bb + swz(b));
      }
  };
  auto mma = [&](int qm, int qn, const bf16x8* bf) {
    __builtin_amdgcn_s_setprio(1);
#pragma unroll
    for (int mi = 0; mi < 4; ++mi)
#pragma unroll
      for (int nj = 0; nj < 2; ++nj)
#pragma unroll
        for (int ks = 0; ks < 2; ++ks)
          acc[qm * 4 + mi][qn * 2 + nj] = __builtin_amdgcn_mfma_f32_16x16x32_bf16(
              aF[mi * 2 + ks], bf[nj * 2 + ks], acc[qm * 4 + mi][qn * 2 + nj], 0, 0, 0);
    __builtin_amdgcn_s_setprio(0);
  };

  // One iteration = K-tiles a (dbuf0, phases 1-4) and a+1 (dbuf1, phases
  // 5-8), quadrants (0,0),(0,1),(1,1),(1,0) per K-tile. Stage slots (one
  // half-tile per phase; write-safe: region last-reads are B:ph2, A:ph3
  // within each K-tile's 4 phases; every stage issues >=1 barrier later):
  //   ph1: A(a+1)h0   ph2: A(a+1)h1   ph3: B(a+2)h0   ph4: B(a+2)h1
  //   ph5: A(a+2)h0   ph6: A(a+2)h1   ph7: B(a+3)h0   ph8: B(a+3)h1
  // Ledger (2 loads/phase): vmcnt(4)@ph4 certifies thru ph2 (A(a+1) +
  // earlier) for phases 5-8; vmcnt(4)@ph8 certifies thru ph6 (A,B(a+2))
  // for the next iteration's phases 1-4. Never drained to 0 mid-loop.
  auto iter = [&](int a, bool f) {
    const int b = a + 1;
    // ph1
    rdA(0, 0); rdB(0, 0, bLo);
    stageA(b, 0);
    BAR(); mma(0, 0, bLo); BAR();
    // ph2
    rdB(0, 1, bHi);
    stageA(b, 1);
    BAR(); mma(0, 1, bHi); BAR();
    // ph3
    rdA(0, 1);
    if (f) stageB(a + 2, 0);
    BAR(); mma(1, 1, bHi); BAR();
    // ph4
    if (f) stageB(a + 2, 1);
    BAR(); mma(1, 0, bLo);
    if (f) { asm volatile("s_waitcnt vmcnt(4)" ::: "memory"); }
    else   { asm volatile("s_waitcnt vmcnt(0)" ::: "memory"); }
    BAR();
    // ph5
    rdA(1, 0); rdB(1, 0, bLo);
    if (f) stageA(a + 2, 0);
    BAR(); mma(0, 0, bLo); BAR();
    // ph6
    rdB(1, 1, bHi);
    if (f) stageA(a + 2, 1);
    BAR(); mma(0, 1, bHi); BAR();
    // ph7
    rdA(1, 1);
    if (f) stageB(a + 3, 0);
    BAR(); mma(1, 1, bHi); BAR();
    // ph8
    if (f) stageB(a + 3, 1);
    BAR(); mma(1, 0, bLo);
    if (f) { asm volatile("s_waitcnt vmcnt(4)" ::: "memory"); }
    BAR();
  };

  // prologue: B(0), A(0), B(1) = 12 loads; vmcnt(4) leaves B(1) in flight.
  stageB(0, 0); stageB(0, 1);
  stageA(0, 0); stageA(0, 1);
  stageB(1, 0); stageB(1, 1);
  asm volatile("s_waitcnt vmcnt(4)" ::: "memory");
  BAR();

  for (int it = 0; it < NIT - 1; ++it) iter(2 * it, true);
  iter(NT - 2, false);

  // epilogue: C/D layout col=lane&15, row=(lane>>4)*4+reg (m89/m91)
  const int r0 = (lane >> 4) * 4;
#pragma unroll
  for (int m = 0; m < 8; ++m) {
#pragma unroll
    for (int r = 0; r < 4; ++r) {
      size_t row = (size_t)(rowBase + wr * 128 + m * 16 + r0 + r);
      float* po = out + row * N_DIM + colBase + wc * 64 + fr;
#pragma unroll
      for (int n = 0; n < 4; ++n)
        po[n * 16] = acc[m][n][r] + bias_v[n];
    }
  }
}

extern "C" void kernel_launch(void* const* d_in, const int* in_sizes, int n_in,
                              void* d_out, int out_size, void* d_ws, size_t ws_size,
                              hipStream_t stream) {
  const float* x = (const float*)d_in[0];   // [8192][4096]
  const float* w = (const float*)d_in[1];   // [11008][4096]
  const float* sc = (const float*)d_in[2];  // [11008]
  const float* bi = (const float*)d_in[3];  // [11008]
  float* out = (float*)d_out;

  const size_t xe = (size_t)M_DIM * K_DIM;
  const size_t we = (size_t)N_DIM * K_DIM;
  unsigned short* xb = (unsigned short*)d_ws;
  unsigned short* wb = xb + xe;

  cvt_x_kernel<<<(unsigned)(xe / 8 / 256), 256, 0, stream>>>(x, xb);
  cvt_w_kernel<<<(unsigned)(we / 8 / 256), 256, 0, stream>>>(w, sc, wb);
  gemm_kernel<<<NWG, 512, 0, stream>>>(xb, wb, bi, out);
}

// Round 12
// 918.977 us; speedup vs baseline: 1.3812x; 1.0073x over previous
//
#include <hip/hip_runtime.h>

// y[m][n] = sum_k x[m][k] * (w[n][k]*scale[n]) + bias[n]
// M=8192, N=11008, K=4096. fp32 in/out, bf16 MFMA compute.
//
// 8-phase m201-style schedule, R10-verified, with ph3+ph4 / ph7+ph8 merged
// (those phases had zero ds_reads): 6 barriers per K-tile instead of 8.
// 256x256 tile, 8 waves (2Mx4N), BK=64, double-buffered LDS (128 KB).
// Per phase: {ds_reads + stage one half-tile -> barrier -> MFMA quadrant(s),
// stage between clusters -> barrier}; counted vmcnt(4) once per K-tile
// (never 0 mid-loop). Ledger identical to R10. Read-side XOR swizzle (T2,
// 0 conflicts measured), XCD block swizzle (T1), setprio (T5).
#define M_DIM 8192
#define N_DIM 11008
#define K_DIM 4096
#define BM 256
#define BN 256
#define BK 64
#define NT (K_DIM / BK)   // 64 K-tiles
#define NIT (NT / 2)      // 32 iterations, 2 K-tiles each
#define TM (M_DIM / BM)   // 32
#define TN (N_DIM / BN)   // 43
#define NWG (TM * TN)     // 1376 (divisible by 8)

typedef __attribute__((ext_vector_type(8))) short bf16x8;
typedef __attribute__((ext_vector_type(8))) unsigned short u16x8;
typedef __attribute__((ext_vector_type(4))) float f32x4;

__device__ __forceinline__ unsigned short f2bf(float f) {
  union { float f; unsigned u; } v; v.f = f;
  unsigned r = v.u + 0x7FFFu + ((v.u >> 16) & 1u);  // RNE
  return (unsigned short)(r >> 16);
}

__device__ __forceinline__ void gload_lds16(const unsigned short* g, unsigned short* l) {
  __builtin_amdgcn_global_load_lds(
      (const __attribute__((address_space(1))) void*)g,
      (__attribute__((address_space(3))) void*)l, 16, 0, 0);
}

// Involution swizzle within a 16 KB half-tile (128 rows x 128 B): XOR the
// 16B-unit index (bits 4-6) with row bits 0-2 (bits 7-9). 16-lane frag reads
// spread across all banks (2 lanes/bank = free, m136; 0 conflicts measured).
__device__ __forceinline__ int swz(int b) { return b ^ (((b >> 7) & 7) << 4); }

#define BAR() asm volatile("s_barrier" ::: "memory")

// ---- pre-convert kernels (memory-bound) ----
__global__ void cvt_x_kernel(const float* __restrict__ in, unsigned short* __restrict__ o) {
  size_t i = (size_t)blockIdx.x * 256 + threadIdx.x;
  const float4* p = (const float4*)in + i * 2;
  float4 f0 = p[0], f1 = p[1];
  u16x8 v;
  v[0] = f2bf(f0.x); v[1] = f2bf(f0.y); v[2] = f2bf(f0.z); v[3] = f2bf(f0.w);
  v[4] = f2bf(f1.x); v[5] = f2bf(f1.y); v[6] = f2bf(f1.z); v[7] = f2bf(f1.w);
  *((u16x8*)o + i) = v;
}

__global__ void cvt_w_kernel(const float* __restrict__ in, const float* __restrict__ sc,
                             unsigned short* __restrict__ o) {
  size_t i = (size_t)blockIdx.x * 256 + threadIdx.x;
  float s = sc[i >> 9];  // 4096/8 = 512 packs per row
  const float4* p = (const float4*)in + i * 2;
  float4 f0 = p[0], f1 = p[1];
  u16x8 v;
  v[0] = f2bf(f0.x * s); v[1] = f2bf(f0.y * s); v[2] = f2bf(f0.z * s); v[3] = f2bf(f0.w * s);
  v[4] = f2bf(f1.x * s); v[5] = f2bf(f1.y * s); v[6] = f2bf(f1.z * s); v[7] = f2bf(f1.w * s);
  *((u16x8*)o + i) = v;
}

// ---- GEMM ----
__launch_bounds__(512, 2)
__global__ void gemm_kernel(const unsigned short* __restrict__ xb,
                            const unsigned short* __restrict__ wb,
                            const float* __restrict__ bias,
                            float* __restrict__ out) {
  // [dbuf][half]: half-tile = 128 rows x 64 k bf16 = 16 KB. Total 128 KB.
  __shared__ unsigned short As[2][2][8192];
  __shared__ unsigned short Bs[2][2][8192];

  const int tid = threadIdx.x;
  const int lane = tid & 63;
  const int wave = tid >> 6;
  const int wr = wave >> 2;   // 0..1 -> 128-row half of A (= A half index)
  const int wc = wave & 3;    // 0..3 -> 64-col slice of B (half = wc>>1)

  // T1: XCD-aware swizzle (bijective, NWG%8==0), column-major within chunk.
  int orig = blockIdx.x;
  int wg = (orig & 7) * (NWG / 8) + (orig >> 3);
  int bx = wg / TM;           // N tile 0..42
  int by = wg % TM;           // M tile 0..31
  const int rowBase = by * BM;
  const int colBase = bx * BN;

  f32x4 acc[8][4] = {};

  const int fr = lane & 15;
  const int q16 = (lane >> 4) * 16;  // byte col of the 8-k sub-frag

  float bias_v[4];
#pragma unroll
  for (int n = 0; n < 4; ++n)
    bias_v[n] = bias[colBase + wc * 64 + n * 16 + fr];

  // staging: half-tile = 16 KB = 512 threads x 2 x 16 B. Linear LDS dest,
  // pre-swizzled global source (rule #21: same involution both sides).
  const int L0 = tid * 16, L1 = L0 + 8192;
  const int S0 = swz(L0), S1 = swz(L1);
  const int sr0 = S0 >> 7, sc0_ = (S0 & 127) >> 1;
  const int sr1 = S1 >> 7, sc1_ = (S1 & 127) >> 1;

  auto stageA = [&](int kt, int half) {
    const unsigned short* src =
        xb + (size_t)(rowBase + half * 128) * K_DIM + (size_t)kt * BK;
    unsigned short* dst = &As[kt & 1][half][0];
    gload_lds16(src + (size_t)sr0 * K_DIM + sc0_, dst + (L0 >> 1));
    gload_lds16(src + (size_t)sr1 * K_DIM + sc1_, dst + (L1 >> 1));
  };
  auto stageB = [&](int kt, int half) {
    const unsigned short* src =
        wb + (size_t)(colBase + half * 128) * K_DIM + (size_t)kt * BK;
    unsigned short* dst = &Bs[kt & 1][half][0];
    gload_lds16(src + (size_t)sr0 * K_DIM + sc0_, dst + (L0 >> 1));
    gload_lds16(src + (size_t)sr1 * K_DIM + sc1_, dst + (L1 >> 1));
  };

  bf16x8 aF[8], bLo[4], bHi[4];

  auto rdA = [&](int d, int qm) {
    const char* Ab = (const char*)&As[d][wr][0];
#pragma unroll
    for (int mi = 0; mi < 4; ++mi)
#pragma unroll
      for (int ks = 0; ks < 2; ++ks) {
        int b = (qm * 64 + mi * 16 + fr) * 128 + ks * 64 + q16;
        aF[mi * 2 + ks] = *(const bf16x8*)(Ab + swz(b));
      }
  };
  auto rdB = [&](int d, int qn, bf16x8* bf) {
    const char* Bb = (const char*)&Bs[d][wc >> 1][0];
#pragma unroll
    for (int nj = 0; nj < 2; ++nj)
#pragma unroll
      for (int ks = 0; ks < 2; ++ks) {
        int b = ((wc & 1) * 64 + qn * 32 + nj * 16 + fr) * 128 + ks * 64 + q16;
        bf[nj * 2 + ks] = *(const bf16x8*)(Bb + swz(b));
      }
  };
  auto mma = [&](int qm, int qn, const bf16x8* bf) {
    __builtin_amdgcn_s_setprio(1);
#pragma unroll
    for (int mi = 0; mi < 4; ++mi)
#pragma unroll
      for (int nj = 0; nj < 2; ++nj)
#pragma unroll
        for (int ks = 0; ks < 2; ++ks)
          acc[qm * 4 + mi][qn * 2 + nj] = __builtin_amdgcn_mfma_f32_16x16x32_bf16(
              aF[mi * 2 + ks], bf[nj * 2 + ks], acc[qm * 4 + mi][qn * 2 + nj], 0, 0, 0);
    __builtin_amdgcn_s_setprio(0);
  };

  // One iteration = K-tiles a (dbuf0) and a+1 (dbuf1); quadrant order per
  // K-tile (0,0),(0,1),(1,1),(1,0). ph3+ph4 / ph7+ph8 merged (no ds_reads
  // in the old ph4/ph8): 6 barriers per K-tile. Stage slots unchanged:
  //   ph1: A(a+1)h0  ph2: A(a+1)h1  ph3': B(a+2)h0 (pre-BAR) + B(a+2)h1
  //        (between MFMA clusters)
  //   ph5: A(a+2)h0  ph6: A(a+2)h1  ph7': B(a+3)h0 + B(a+3)h1 (same shape)
  // Write-safety: each staged region's last ds_read completed before the
  // barrier preceding the stage issue. Ledger: at each merged-phase wait,
  // outstanding = B(next)h0+h1 = 4 -> vmcnt(4) certifies all A-staging for
  // the next dbuf's reads. Never drained to 0 mid-loop.
  auto iter = [&](int a, bool f) {
    const int b = a + 1;
    // ph1
    rdA(0, 0); rdB(0, 0, bLo);
    stageA(b, 0);
    BAR(); mma(0, 0, bLo); BAR();
    // ph2
    rdB(0, 1, bHi);
    stageA(b, 1);
    BAR(); mma(0, 1, bHi); BAR();
    // ph3' (merged ph3+ph4)
    rdA(0, 1);
    if (f) stageB(a + 2, 0);
    BAR();
    mma(1, 1, bHi);
    if (f) stageB(a + 2, 1);
    mma(1, 0, bLo);
    if (f) { asm volatile("s_waitcnt vmcnt(4)" ::: "memory"); }
    else   { asm volatile("s_waitcnt vmcnt(0)" ::: "memory"); }
    BAR();
    // ph5
    rdA(1, 0); rdB(1, 0, bLo);
    if (f) stageA(a + 2, 0);
    BAR(); mma(0, 0, bLo); BAR();
    // ph6
    rdB(1, 1, bHi);
    if (f) stageA(a + 2, 1);
    BAR(); mma(0, 1, bHi); BAR();
    // ph7' (merged ph7+ph8)
    rdA(1, 1);
    if (f) stageB(a + 3, 0);
    BAR();
    mma(1, 1, bHi);
    if (f) stageB(a + 3, 1);
    mma(1, 0, bLo);
    if (f) { asm volatile("s_waitcnt vmcnt(4)" ::: "memory"); }
    BAR();
  };

  // prologue: B(0), A(0), B(1) = 12 loads; vmcnt(4) leaves B(1) in flight.
  stageB(0, 0); stageB(0, 1);
  stageA(0, 0); stageA(0, 1);
  stageB(1, 0); stageB(1, 1);
  asm volatile("s_waitcnt vmcnt(4)" ::: "memory");
  BAR();

  for (int it = 0; it < NIT - 1; ++it) iter(2 * it, true);
  iter(NT - 2, false);

  // epilogue: C/D layout col=lane&15, row=(lane>>4)*4+reg (m89/m91)
  const int r0 = (lane >> 4) * 4;
#pragma unroll
  for (int m = 0; m < 8; ++m) {
#pragma unroll
    for (int r = 0; r < 4; ++r) {
      size_t row = (size_t)(rowBase + wr * 128 + m * 16 + r0 + r);
      float* po = out + row * N_DIM + colBase + wc * 64 + fr;
#pragma unroll
      for (int n = 0; n < 4; ++n)
        po[n * 16] = acc[m][n][r] + bias_v[n];
    }
  }
}

extern "C" void kernel_launch(void* const* d_in, const int* in_sizes, int n_in,
                              void* d_out, int out_size, void* d_ws, size_t ws_size,
                              hipStream_t stream) {
  const float* x = (const float*)d_in[0];   // [8192][4096]
  const float* w = (const float*)d_in[1];   // [11008][4096]
  const float* sc = (const float*)d_in[2];  // [11008]
  const float* bi = (const float*)d_in[3];  // [11008]
  float* out = (float*)d_out;

  const size_t xe = (size_t)M_DIM * K_DIM;
  const size_t we = (size_t)N_DIM * K_DIM;
  unsigned short* xb = (unsigned short*)d_ws;
  unsigned short* wb = xb + xe;

  cvt_x_kernel<<<(unsigned)(xe / 8 / 256), 256, 0, stream>>>(x, xb);
  cvt_w_kernel<<<(unsigned)(we / 8 / 256), 256, 0, stream>>>(w, sc, wb);
  gemm_kernel<<<NWG, 512, 0, stream>>>(xb, wb, bi, out);
}